// Round 3
// baseline (75.251 us; speedup 1.0000x reference)
//
#include <hip/hip_runtime.h>
#include <hip/hip_bf16.h>
#include <cstdint>
#include <cstddef>

typedef short short8 __attribute__((ext_vector_type(8)));
typedef float f32x4 __attribute__((ext_vector_type(4)));

constexpr int NR = 8192;   // rows of a  (output rows)
constexpr int MR = 8192;   // rows of b  (output cols)
constexpr int D  = 64;     // feature dim (K)

__device__ inline short f2bf(float f) {
  uint32_t u = __float_as_uint(f);
  u += 0x7fffu + ((u >> 16) & 1u);   // RNE to bf16
  return (short)(u >> 16);
}

// ---------------------------------------------------------------------------
// Single fused kernel: per-block 128x128 output tile.
//   - load fp32 A/B fragment slices straight from global (L2/L3-resident),
//   - in-register row-norm (shfl_xor over the 4 k-slice lane groups),
//   - scale + RNE-cast to bf16 fragments,
//   - 32x mfma_f32_16x16x32_bf16 into 4x4 f32x4 accumulators per wave,
//   - LDS-bounce epilogue -> contiguous float4 nontemporal stores.
//
// Fragment layouts (gfx950, HW-verified):
//   A/B in : lane l holds 8 contiguous k-elems: row = l&15, k = (l>>4)*8 ..+7
//   C/D out: col = l&15, row = (l>>4)*4 + reg
// ---------------------------------------------------------------------------
__global__ __launch_bounds__(256, 2) void cos_fused(
    const float* __restrict__ A, const float* __restrict__ B,
    float* __restrict__ C) {
  // per-wave private 64x64 fp32 tile; row stride 68 -> only 2-way bank alias
  __shared__ float lds[4][64][68];   // 68 KiB

  int tile = blockIdx.x;
  int tm = tile >> 6;            // 64 tiles along output rows
  int tn = tile & 63;            // 64 tiles along output cols
  int wid  = threadIdx.x >> 6;   // 0..3
  int lane = threadIdx.x & 63;
  int wr = wid >> 1, wc = wid & 1;

  int R0 = tm * 128 + wr * 64;   // output row base for this wave (a rows)
  int C0 = tn * 128 + wc * 64;   // output col base for this wave (b rows)

  int lrow = lane & 15;
  int lk8  = (lane >> 4) * 8;    // k-slice base within a 32-wide k-step

  short8 af[4][2], bf[4][2];

  // ---- A fragments: load fp32, normalize row, cast bf16 ----
#pragma unroll
  for (int i = 0; i < 4; ++i) {
    const float* p = A + (size_t)(R0 + i * 16 + lrow) * D + lk8;
    float v[16];
    *reinterpret_cast<float4*>(v)      = *reinterpret_cast<const float4*>(p);
    *reinterpret_cast<float4*>(v + 4)  = *reinterpret_cast<const float4*>(p + 4);
    *reinterpret_cast<float4*>(v + 8)  = *reinterpret_cast<const float4*>(p + 32);
    *reinterpret_cast<float4*>(v + 12) = *reinterpret_cast<const float4*>(p + 36);
    float ss = 0.f;
#pragma unroll
    for (int e = 0; e < 16; ++e) ss += v[e] * v[e];
    // lanes {l, l^16, l^32, l^48} hold the 4 k-slices of the same row
    ss += __shfl_xor(ss, 16);
    ss += __shfl_xor(ss, 32);
    float sc = rsqrtf(ss);
    short t[16];
#pragma unroll
    for (int e = 0; e < 16; ++e) t[e] = f2bf(v[e] * sc);
    af[i][0] = *reinterpret_cast<short8*>(t);
    af[i][1] = *reinterpret_cast<short8*>(t + 8);
  }

  // ---- B fragments: same, over b rows (output cols) ----
#pragma unroll
  for (int j = 0; j < 4; ++j) {
    const float* p = B + (size_t)(C0 + j * 16 + lrow) * D + lk8;
    float v[16];
    *reinterpret_cast<float4*>(v)      = *reinterpret_cast<const float4*>(p);
    *reinterpret_cast<float4*>(v + 4)  = *reinterpret_cast<const float4*>(p + 4);
    *reinterpret_cast<float4*>(v + 8)  = *reinterpret_cast<const float4*>(p + 32);
    *reinterpret_cast<float4*>(v + 12) = *reinterpret_cast<const float4*>(p + 36);
    float ss = 0.f;
#pragma unroll
    for (int e = 0; e < 16; ++e) ss += v[e] * v[e];
    ss += __shfl_xor(ss, 16);
    ss += __shfl_xor(ss, 32);
    float sc = rsqrtf(ss);
    short t[16];
#pragma unroll
    for (int e = 0; e < 16; ++e) t[e] = f2bf(v[e] * sc);
    bf[j][0] = *reinterpret_cast<short8*>(t);
    bf[j][1] = *reinterpret_cast<short8*>(t + 8);
  }

  // ---- MFMA: K=64 as two 32-wide steps ----
  f32x4 acc[4][4] = {};
#pragma unroll
  for (int s = 0; s < 2; ++s)
#pragma unroll
    for (int i = 0; i < 4; ++i)
#pragma unroll
      for (int j = 0; j < 4; ++j)
        acc[i][j] = __builtin_amdgcn_mfma_f32_16x16x32_bf16(
            af[i][s], bf[j][s], acc[i][j], 0, 0, 0);

  // ---- epilogue: wave-private LDS bounce -> contiguous f32x4 nt stores ----
  int crow = (lane >> 4) * 4;
  int ccol = lane & 15;
#pragma unroll
  for (int i = 0; i < 4; ++i)
#pragma unroll
    for (int j = 0; j < 4; ++j)
#pragma unroll
      for (int r = 0; r < 4; ++r)
        lds[wid][i * 16 + crow + r][j * 16 + ccol] = acc[i][j][r];
  // no barrier: wave-private region; compiler orders ds_write->ds_read

#pragma unroll
  for (int it = 0; it < 16; ++it) {
    int row = it * 4 + (lane >> 4);
    int col = (lane & 15) * 4;
    f32x4 o = *reinterpret_cast<const f32x4*>(&lds[wid][row][col]);
    f32x4* dst = reinterpret_cast<f32x4*>(
        C + (size_t)(R0 + row) * MR + (C0 + col));
    __builtin_nontemporal_store(o, dst);
  }
}

// ---------------------------------------------------------------------------
extern "C" void kernel_launch(void* const* d_in, const int* in_sizes, int n_in,
                              void* d_out, int out_size, void* d_ws, size_t ws_size,
                              hipStream_t stream) {
  const float* a = (const float*)d_in[0];
  const float* b = (const float*)d_in[1];
  float* out = (float*)d_out;

  // (8192/128)^2 = 4096 tiles
  cos_fused<<<4096, 256, 0, stream>>>(a, b, out);
}

// Round 4
// 64.264 us; speedup vs baseline: 1.1710x; 1.1710x over previous
//
#include <hip/hip_runtime.h>
#include <hip/hip_bf16.h>
#include <cstdint>
#include <cstddef>

typedef short short8 __attribute__((ext_vector_type(8)));
typedef float f32x4 __attribute__((ext_vector_type(4)));

constexpr int Nrows = 8192;   // rows of a
constexpr int Mrows = 8192;   // rows of b
constexpr int Dim   = 64;     // feature dim (K)

// ---------------------------------------------------------------------------
// Kernel 1: per-row L2 norm, scale row to unit length, cast to bf16 (RNE).
// 16 lanes per row, each lane owns one float4 (16*4 = 64 elements).
// ---------------------------------------------------------------------------
__global__ __launch_bounds__(256) void cos_norm_scale(
    const float* __restrict__ a, const float* __restrict__ b,
    short* __restrict__ as_, short* __restrict__ bs_) {
  int gid = blockIdx.x * 256 + threadIdx.x;
  int row = gid >> 4;      // 16 threads per row
  int sub = gid & 15;      // which float4 of the row
  const float* src = a;
  short* dst = as_;
  if (row >= Nrows) { src = b; dst = bs_; row -= Nrows; }

  float4 v = reinterpret_cast<const float4*>(src + (size_t)row * Dim)[sub];
  float ss = v.x * v.x + v.y * v.y + v.z * v.z + v.w * v.w;
  ss += __shfl_xor(ss, 1);
  ss += __shfl_xor(ss, 2);
  ss += __shfl_xor(ss, 4);
  ss += __shfl_xor(ss, 8);
  float scale = rsqrtf(ss);

  float sv[4] = {v.x * scale, v.y * scale, v.z * scale, v.w * scale};
  short4 o;
  short* op = reinterpret_cast<short*>(&o);
#pragma unroll
  for (int i = 0; i < 4; ++i) {
    uint32_t u = __float_as_uint(sv[i]);
    u += 0x7fffu + ((u >> 16) & 1u);   // RNE to bf16
    op[i] = (short)(u >> 16);
  }
  reinterpret_cast<short4*>(dst + (size_t)row * Dim)[sub] = o;
}

// ---------------------------------------------------------------------------
// Kernel 2: C = A_unit @ B_unit^T via mfma_f32_16x16x32_bf16.
// Identical to the proven R1 kernel EXCEPT the epilogue: instead of 64 scalar
// 4B stores per wave, bounce the 64x64 wave tile through LDS in two 32-row
// halves (34 KiB/block total) and emit contiguous f32x4 stores.
//
// Fragment layouts (gfx950, HW-verified):
//   A/B in : lane l holds 8 contiguous k-elems: row=l&15, k=(l>>4)*8 .. +7
//   C/D out: col = l&15, row = (l>>4)*4 + reg
// ---------------------------------------------------------------------------
__global__ __launch_bounds__(256) void cos_gemm(
    const short* __restrict__ A, const short* __restrict__ B,
    float* __restrict__ C) {
  // per-wave private 32x64 bounce buffer; stride 68 -> 2-way alias only (free)
  __shared__ float lds[4][32][68];   // 34 KiB

  int tile = blockIdx.x;
  int tm = tile >> 6;
  int tn = tile & 63;
  int wid  = threadIdx.x >> 6;
  int lane = threadIdx.x & 63;
  int wr = wid >> 1, wc = wid & 1;

  int R0 = tm * 128 + wr * 64;
  int C0 = tn * 128 + wc * 64;

  int lrow = lane & 15;
  int lk8  = (lane >> 4) * 8;

  f32x4 acc[4][4] = {};

#pragma unroll
  for (int s = 0; s < 2; ++s) {        // K steps of 32
    short8 af[4], bf[4];
#pragma unroll
    for (int i = 0; i < 4; ++i)
      af[i] = *reinterpret_cast<const short8*>(
          A + (size_t)(R0 + i * 16 + lrow) * Dim + s * 32 + lk8);
#pragma unroll
    for (int j = 0; j < 4; ++j)
      bf[j] = *reinterpret_cast<const short8*>(
          B + (size_t)(C0 + j * 16 + lrow) * Dim + s * 32 + lk8);
#pragma unroll
    for (int i = 0; i < 4; ++i)
#pragma unroll
      for (int j = 0; j < 4; ++j)
        acc[i][j] = __builtin_amdgcn_mfma_f32_16x16x32_bf16(
            af[i], bf[j], acc[i][j], 0, 0, 0);
  }

  // ---- epilogue: two 32-row halves through wave-private LDS ----
  int crow = (lane >> 4) * 4;
  int ccol = lane & 15;
#pragma unroll
  for (int h = 0; h < 2; ++h) {
#pragma unroll
    for (int i2 = 0; i2 < 2; ++i2) {
      int i = h * 2 + i2;
#pragma unroll
      for (int j = 0; j < 4; ++j)
#pragma unroll
        for (int r = 0; r < 4; ++r)
          lds[wid][i2 * 16 + crow + r][j * 16 + ccol] = acc[i][j][r];
    }
    // wave-private region: no barrier; in-wave DS ordering + lgkmcnt suffice
#pragma unroll
    for (int it = 0; it < 8; ++it) {
      int row = it * 4 + (lane >> 4);
      int col = (lane & 15) * 4;
      f32x4 o = *reinterpret_cast<const f32x4*>(&lds[wid][row][col]);
      *reinterpret_cast<f32x4*>(
          C + (size_t)(R0 + h * 32 + row) * Mrows + (C0 + col)) = o;
    }
  }
}

// ---------------------------------------------------------------------------
extern "C" void kernel_launch(void* const* d_in, const int* in_sizes, int n_in,
                              void* d_out, int out_size, void* d_ws, size_t ws_size,
                              hipStream_t stream) {
  const float* a = (const float*)d_in[0];
  const float* b = (const float*)d_in[1];
  float* out = (float*)d_out;

  short* as_ = (short*)d_ws;                       // 8192*64 bf16 = 1 MB
  short* bs_ = as_ + (size_t)Nrows * Dim;          // next 1 MB

  cos_norm_scale<<<1024, 256, 0, stream>>>(a, b, as_, bs_);
  cos_gemm<<<4096, 256, 0, stream>>>(as_, bs_, out);
}